// Round 2
// baseline (211.025 us; speedup 1.0000x reference)
//
#include <hip/hip_runtime.h>
#include <math.h>

#define BLOCK 256
#define UNROLL 8

// theta^2 for rel = qinv(a) * idd.
// rel is (nearly) unit-norm, so atan2(|v|, w) == acos(w / |rel|).
// Hastings acos approx: acos(x) = sqrt(1-x)*(a0 + a1 x + a2 x^2 + a3 x^3),
// x in [0,1]; acos(-x) = pi - acos(x). Max abs err ~6.8e-5 rad.
__device__ __forceinline__ float theta_sq(float4 qa, float4 qb) {
    float w1 = qa.x, x1 = -qa.y, y1 = -qa.z, z1 = -qa.w;
    float w2 = qb.x, x2 = qb.y,  y2 = qb.z,  z2 = qb.w;
    float w  = w1*w2 - (x1*x2 + y1*y2 + z1*z2);
    float vx = w1*x2 + w2*x1 + (y1*z2 - z1*y2);
    float vy = w1*y2 + w2*y1 + (z1*x2 - x1*z2);
    float vz = w1*z2 + w2*z1 + (x1*y2 - y1*x2);
    float nv2 = vx*vx + vy*vy + vz*vz;
    float nv  = sqrtf(nv2);
    if (nv < 1e-6f) {                    // reference small-angle branch
        float s = 2.0f / w;
        return nv2 * s * s;
    }
    float rn = rsqrtf(w*w + nv2);        // ~1.0, exact normalize
    float c  = w * rn;                   // cos(theta/2), in [-1,1]
    float ac = fabsf(c);
    float p  = ((-0.0187293f*ac + 0.0742610f)*ac - 0.2121144f)*ac + 1.5707288f;
    float r  = sqrtf(fmaxf(1.0f - ac, 0.0f)) * p;           // acos(|c|)
    float acosc = (c >= 0.0f) ? r : (3.14159265358979f - r);
    float theta = 2.0f * acosc;
    return theta * theta;
}

__global__ __launch_bounds__(BLOCK) void geo_loss_kernel(
        const float4* __restrict__ a,
        const float4* __restrict__ idd,
        float* __restrict__ ws,          // ws[0]=sum, ws[1]=counter(uint)
        float* __restrict__ out,
        int n, int nblocks) {
    const int stride = gridDim.x * BLOCK;
    const int i0 = blockIdx.x * BLOCK + threadIdx.x;
    float acc = 0.0f;

    for (int base = i0; base < n; base += UNROLL * stride) {
        float4 qa[UNROLL], qb[UNROLL];
        // issue all loads back-to-back (exec-masked, fully coalesced per k)
        #pragma unroll
        for (int k = 0; k < UNROLL; k++) {
            int idx = base + k * stride;
            if (idx < n) { qa[k] = a[idx]; qb[k] = idd[idx]; }
        }
        #pragma unroll
        for (int k = 0; k < UNROLL; k++) {
            int idx = base + k * stride;
            if (idx < n) acc += theta_sq(qa[k], qb[k]);
        }
    }

    // wave-64 reduction
    #pragma unroll
    for (int off = 32; off > 0; off >>= 1)
        acc += __shfl_down(acc, off, 64);
    __shared__ float smem[BLOCK / 64];
    int lane = threadIdx.x & 63;
    int wid  = threadIdx.x >> 6;
    if (lane == 0) smem[wid] = acc;
    __syncthreads();

    if (threadIdx.x == 0) {
        float s = smem[0] + smem[1] + smem[2] + smem[3];
        atomicAdd(ws, s);
        __threadfence();                                   // order sum before counter
        unsigned int old = atomicAdd((unsigned int*)(ws + 1), 1u);
        if (old == (unsigned int)nblocks - 1u) {           // last block finalizes
            float total = atomicAdd(ws, 0.0f);             // coherent read
            out[0] = sqrtf(total);
        }
    }
}

extern "C" void kernel_launch(void* const* d_in, const int* in_sizes, int n_in,
                              void* d_out, int out_size, void* d_ws, size_t ws_size,
                              hipStream_t stream) {
    const float4* a   = (const float4*)d_in[0];
    const float4* idd = (const float4*)d_in[1];
    int n = in_sizes[0] / 4;             // 4,000,000 quaternions
    float* ws = (float*)d_ws;

    hipMemsetAsync(ws, 0, 2 * sizeof(float), stream);      // sum + counter

    int grid = (n + BLOCK * UNROLL - 1) / (BLOCK * UNROLL);  // 1954: one pass
    geo_loss_kernel<<<grid, BLOCK, 0, stream>>>(a, idd, ws, (float*)d_out, n, grid);
}

// Round 3
// 142.912 us; speedup vs baseline: 1.4766x; 1.4766x over previous
//
#include <hip/hip_runtime.h>
#include <math.h>

#define BLOCK 256
#define UNROLL 8
#define TILE (BLOCK * UNROLL)   // 2048 elements per block, contiguous

// theta^2 for rel = qinv(a) * idd.
// rel is (nearly) unit-norm, so atan2(|v|, w) == acos(w / |rel|).
// Hastings acos approx, max abs err ~6.8e-5 rad (tolerance is 2% relative).
__device__ __forceinline__ float theta_sq(float4 qa, float4 qb) {
    float w1 = qa.x, x1 = -qa.y, y1 = -qa.z, z1 = -qa.w;
    float w2 = qb.x, x2 = qb.y,  y2 = qb.z,  z2 = qb.w;
    float w  = w1*w2 - (x1*x2 + y1*y2 + z1*z2);
    float vx = w1*x2 + w2*x1 + (y1*z2 - z1*y2);
    float vy = w1*y2 + w2*y1 + (z1*x2 - x1*z2);
    float vz = w1*z2 + w2*z1 + (x1*y2 - y1*x2);
    float nv2 = vx*vx + vy*vy + vz*vz;
    float nv  = sqrtf(nv2);
    if (nv < 1e-6f) {                    // reference small-angle branch
        float s = 2.0f / w;
        return nv2 * s * s;
    }
    float rn = rsqrtf(w*w + nv2);        // exact normalize (~1.0)
    float c  = w * rn;                   // cos(theta/2) in [-1,1]
    float ac = fabsf(c);
    float p  = ((-0.0187293f*ac + 0.0742610f)*ac - 0.2121144f)*ac + 1.5707288f;
    float r  = sqrtf(fmaxf(1.0f - ac, 0.0f)) * p;            // acos(|c|)
    float acosc = (c >= 0.0f) ? r : (3.14159265358979f - r);
    float theta = 2.0f * acosc;
    return theta * theta;
}

__global__ __launch_bounds__(BLOCK) void geo_loss_kernel(
        const float4* __restrict__ a,
        const float4* __restrict__ idd,
        float* __restrict__ ws, int n) {
    const int tid  = threadIdx.x;
    const int base = blockIdx.x * TILE + tid;
    float acc = 0.0f;

    if (base + (UNROLL - 1) * BLOCK < n) {
        // full tile — block-uniform branch, zero predication, one load clause
        float4 qa[UNROLL], qb[UNROLL];
        #pragma unroll
        for (int k = 0; k < UNROLL; k++) qa[k] = a[base + k * BLOCK];
        #pragma unroll
        for (int k = 0; k < UNROLL; k++) qb[k] = idd[base + k * BLOCK];
        #pragma unroll
        for (int k = 0; k < UNROLL; k++) acc += theta_sq(qa[k], qb[k]);
    } else {
        // tail block only
        for (int k = 0; k < UNROLL; k++) {
            int idx = base + k * BLOCK;
            if (idx < n) acc += theta_sq(a[idx], idd[idx]);
        }
    }

    // wave-64 reduction
    #pragma unroll
    for (int off = 32; off > 0; off >>= 1)
        acc += __shfl_down(acc, off, 64);
    __shared__ float smem[BLOCK / 64];
    int lane = tid & 63;
    int wid  = tid >> 6;
    if (lane == 0) smem[wid] = acc;
    __syncthreads();
    if (tid == 0) {
        float s = smem[0] + smem[1] + smem[2] + smem[3];
        atomicAdd(ws, s);            // device-scope by default on CDNA
    }
}

__global__ void finalize_kernel(const float* __restrict__ ws,
                                float* __restrict__ out) {
    out[0] = sqrtf(ws[0]);
}

extern "C" void kernel_launch(void* const* d_in, const int* in_sizes, int n_in,
                              void* d_out, int out_size, void* d_ws, size_t ws_size,
                              hipStream_t stream) {
    const float4* a   = (const float4*)d_in[0];
    const float4* idd = (const float4*)d_in[1];
    int n = in_sizes[0] / 4;             // 4,000,000 quaternions
    float* ws = (float*)d_ws;

    hipMemsetAsync(ws, 0, sizeof(float), stream);

    int grid = (n + TILE - 1) / TILE;    // 1954 blocks, one contiguous pass
    geo_loss_kernel<<<grid, BLOCK, 0, stream>>>(a, idd, ws, n);
    finalize_kernel<<<1, 1, 0, stream>>>(ws, (float*)d_out);
}